// Round 12
// baseline (237.909 us; speedup 1.0000x reference)
//
#include <hip/hip_runtime.h>
#include <hip/hip_bf16.h>

#define DIMD 512
#define NEXP 8
#define HIDN 2048
#define NTOK 4096
#define NASG 8192

typedef short bf16x8 __attribute__((ext_vector_type(8)));
typedef float f32x4 __attribute__((ext_vector_type(4)));

__device__ inline unsigned short f2bf(float f) {
  __hip_bfloat16 h = __float2bfloat16(f);
  return __builtin_bit_cast(unsigned short, h);
}

__device__ inline void gl16(const void* g, void* l) {
  __builtin_amdgcn_global_load_lds(
      (const __attribute__((address_space(1))) unsigned int*)g,
      (__attribute__((address_space(3))) unsigned int*)l, 16, 0, 0);
}

// Counted-vmcnt barrier discipline: wait only the OLDER stage's loads.
#define PIPE_WAIT6_BAR() do { \
  asm volatile("s_waitcnt vmcnt(6)" ::: "memory"); \
  __builtin_amdgcn_s_barrier(); \
  __builtin_amdgcn_sched_barrier(0); } while (0)
#define PIPE_WAIT4_BAR() do { \
  asm volatile("s_waitcnt vmcnt(4)" ::: "memory"); \
  __builtin_amdgcn_s_barrier(); \
  __builtin_amdgcn_sched_barrier(0); } while (0)
#define PIPE_WAIT0_BAR() do { \
  asm volatile("s_waitcnt vmcnt(0)" ::: "memory"); \
  __builtin_amdgcn_s_barrier(); \
  __builtin_amdgcn_sched_barrier(0); } while (0)
#define PIPE_POST_BAR() do { \
  asm volatile("" ::: "memory"); \
  __builtin_amdgcn_sched_barrier(0); \
  __builtin_amdgcn_s_barrier(); } while (0)

// ---------- both W transposes in one launch: [E][R][C] fp32 -> [E][C][R] bf16 ----------
__global__ __launch_bounds__(256) void transpose_both_kernel(
    const float* __restrict__ W1, const float* __restrict__ W2,
    unsigned short* __restrict__ w1t, unsigned short* __restrict__ w2t) {
  __shared__ float tile[64][65];
  int z = blockIdx.z;
  int e = z & 7;
  const float* src; unsigned short* dst; int R, C, r0, c0;
  if (z < 8) { src = W1; dst = w1t; R = DIMD; C = HIDN; c0 = blockIdx.x * 64; r0 = blockIdx.y * 64; }
  else       { src = W2; dst = w2t; R = HIDN; C = DIMD; r0 = blockIdx.x * 64; c0 = blockIdx.y * 64; }
  const float* s = src + (size_t)e * R * C;
  unsigned short* d = dst + (size_t)e * R * C;
  // float4 coalesced reads
  for (int i = threadIdx.x; i < 1024; i += 256) {
    int r = i >> 4, c4 = (i & 15) * 4;
    float4 v = *reinterpret_cast<const float4*>(s + (size_t)(r0 + r) * C + (c0 + c4));
    tile[r][c4] = v.x; tile[r][c4 + 1] = v.y; tile[r][c4 + 2] = v.z; tile[r][c4 + 3] = v.w;
  }
  __syncthreads();
  // uint2 packed writes (4 consecutive r per thread)
  for (int i = threadIdx.x; i < 1024; i += 256) {
    int c = i >> 4;
    int r = (i & 15) * 4;
    unsigned u0 = (unsigned)f2bf(tile[r][c]) | ((unsigned)f2bf(tile[r + 1][c]) << 16);
    unsigned u1 = (unsigned)f2bf(tile[r + 2][c]) | ((unsigned)f2bf(tile[r + 3][c]) << 16);
    *reinterpret_cast<uint2*>(d + (size_t)(c0 + c) * R + (r0 + r)) = make_uint2(u0, u1);
  }
}

// ---------- router: logits, softmax, top-2, renorm; emits x in bf16. NO atomics. ----------
__global__ __launch_bounds__(256) void router_kernel(const float* __restrict__ x,
                                                     const float* __restrict__ Wr,
                                                     const float* __restrict__ br,
                                                     int* __restrict__ tidx,
                                                     float* __restrict__ tw,
                                                     unsigned short* __restrict__ xb) {
  int lane = threadIdx.x & 63;
  int n = blockIdx.x * 4 + (threadIdx.x >> 6);
  const float* xr = x + (size_t)n * DIMD;
  unsigned short* xbr = xb + (size_t)n * DIMD;
  float acc[NEXP];
#pragma unroll
  for (int e = 0; e < NEXP; ++e) acc[e] = 0.f;
#pragma unroll
  for (int it = 0; it < 2; ++it) {
    int d0 = it * 256 + lane * 4;
    float4 xv = *reinterpret_cast<const float4*>(xr + d0);
    unsigned p0 = (unsigned)f2bf(xv.x) | ((unsigned)f2bf(xv.y) << 16);
    unsigned p1 = (unsigned)f2bf(xv.z) | ((unsigned)f2bf(xv.w) << 16);
    *reinterpret_cast<uint2*>(xbr + d0) = make_uint2(p0, p1);
    const float* wr = Wr + (size_t)d0 * NEXP;
#pragma unroll
    for (int j = 0; j < 4; ++j) {
      float xj = (&xv.x)[j];
#pragma unroll
      for (int e = 0; e < NEXP; ++e) acc[e] += xj * wr[j * NEXP + e];
    }
  }
#pragma unroll
  for (int e = 0; e < NEXP; ++e) {
    float v = acc[e];
#pragma unroll
    for (int off = 32; off > 0; off >>= 1) v += __shfl_xor(v, off, 64);
    acc[e] = v + br[e];
  }
  if (lane == 0) {
    float m = acc[0];
    for (int e = 1; e < NEXP; ++e) m = fmaxf(m, acc[e]);
    float p[NEXP], s = 0.f;
    for (int e = 0; e < NEXP; ++e) { p[e] = expf(acc[e] - m); s += p[e]; }
    float inv = 1.f / s;
    for (int e = 0; e < NEXP; ++e) p[e] *= inv;
    int i0 = 0; float p0 = p[0];
    for (int e = 1; e < NEXP; ++e) if (p[e] > p0) { p0 = p[e]; i0 = e; }
    int i1 = (i0 == 0) ? 1 : 0; float p1 = p[i1];
    for (int e = 0; e < NEXP; ++e) if (e != i0 && p[e] > p1) { p1 = p[e]; i1 = e; }
    // reference renormalizes by softmax over the top-2 *probabilities*
    float t = expf(p1 - p0);
    float w0 = 1.f / (1.f + t);
    tidx[2 * n] = i0; tidx[2 * n + 1] = i1;
    tw[2 * n] = w0; tw[2 * n + 1] = t * w0;
  }
}

// ---------- route_pack: counts + offsets + stable scatter + lb tail, single block ----------
__global__ __launch_bounds__(1024) void route_pack_kernel(const int* __restrict__ tidx,
                                                          int* __restrict__ off,
                                                          int* __restrict__ list,
                                                          float* __restrict__ out_tail) {
  int tid = threadIdx.x;
  int wv = tid >> 6, lane = tid & 63;

  int ids[8];
#pragma unroll
  for (int j = 0; j < 8; ++j) ids[j] = tidx[tid * 8 + j];

  int c[NEXP];
#pragma unroll
  for (int e = 0; e < NEXP; ++e) c[e] = 0;
#pragma unroll
  for (int j = 0; j < 8; ++j)
#pragma unroll
    for (int e = 0; e < NEXP; ++e) c[e] += (ids[j] == e) ? 1 : 0;

  int inc[NEXP];
#pragma unroll
  for (int e = 0; e < NEXP; ++e) {
    int v = c[e];
#pragma unroll
    for (int d = 1; d < 64; d <<= 1) {
      int t = __shfl_up(v, d, 64);
      if (lane >= d) v += t;
    }
    inc[e] = v;
  }

  __shared__ int wtot[NEXP][16];
  __shared__ int wbase[NEXP][16];
  __shared__ int ebase[NEXP];
  if (lane == 63) {
#pragma unroll
    for (int e = 0; e < NEXP; ++e) wtot[e][wv] = inc[e];
  }
  __syncthreads();
  if (tid == 0) {
    int o = 0;
    float lb = 0.f;
    for (int e = 0; e < NEXP; ++e) {
      int s = 0;
      for (int w = 0; w < 16; ++w) { wbase[e][w] = s; s += wtot[e][w]; }
      ebase[e] = o;
      off[e] = o;
      o += s;
      float l = (float)s / (float)NASG;
      out_tail[1 + e] = l;
      float dd = l - 0.125f;
      lb += dd * dd;
    }
    off[NEXP] = o;
    out_tail[0] = lb;
  }
  __syncthreads();

  int pos[NEXP];
#pragma unroll
  for (int e = 0; e < NEXP; ++e)
    pos[e] = ebase[e] + wbase[e][wv] + (inc[e] - c[e]);

#pragma unroll
  for (int j = 0; j < 8; ++j) {
    int e = ids[j];
    int p = 0;
#pragma unroll
    for (int k = 0; k < NEXP; ++k)
      if (e == k) { p = pos[k]; pos[k] = p + 1; }
    list[p] = tid * 8 + j;
  }
}

// ===== BK=32 tile: row-pair packed LDS, 2-way-free swizzle =====
// byte(r, kq) = (r>>1)*128 + (((kq + (r&1)*4) ^ ((r>>1)&7)) << 4)
// Staged linearly by gl16 from pre-swizzled per-lane global sources.

// ---------- GEMM1: H = gelu(Xg @ W1 + b1); BM=128 BN=256 BK=32, counted-vmcnt dbuf ----------
__global__ __launch_bounds__(256) void gemm1_kernel(
    const unsigned short* __restrict__ xb,
    const unsigned short* __restrict__ w1t,   // [E][2048][512]
    const float* __restrict__ b1,
    const int* __restrict__ off,
    const int* __restrict__ list,
    unsigned short* __restrict__ H) {
  int e = blockIdx.x;                        // linear%8 == e -> expert pinned to one XCD
  int offe = off[e];
  int cnt_e = off[e + 1] - offe;
  int n0 = blockIdx.y * 256;
  int m0 = blockIdx.z * 128;
  if (m0 >= cnt_e) return;

  __shared__ char ldsb[49152];   // 2 x (A 8K | B 16K)

  int tid = threadIdx.x, wv = tid >> 6, lane = tid & 63;
  int rp = lane >> 3, sl = lane & 7;
  int sx = sl ^ rp;
  int rowadd = rp * 2 + (sx >> 2);
  int kq = sx & 3;

  const unsigned short* w1e = w1t + (size_t)e * HIDN * DIMD;
  const unsigned short* asrc[2];
  const unsigned short* bsrc[4];
#pragma unroll
  for (int i = 0; i < 2; ++i) {
    int r = wv * 32 + i * 16 + rowadd;
    int rr = m0 + r;
    int tok = 0;
    if (rr < cnt_e) tok = list[offe + rr] >> 1;
    asrc[i] = xb + (size_t)tok * DIMD + kq * 8;
  }
#pragma unroll
  for (int i = 0; i < 4; ++i) {
    int r = wv * 64 + i * 16 + rowadd;       // B: 256 rows, 64 per wave
    bsrc[i] = w1e + (size_t)(n0 + r) * DIMD + kq * 8;
  }
  int dstA0 = wv * 2048;
  int dstA1 = wv * 2048 + 1024;
  int dstB = 8192 + wv * 4096;

  f32x4 zero = {0.f, 0.f, 0.f, 0.f};
  f32x4 acc[4][8];
#pragma unroll
  for (int m = 0; m < 4; ++m)
#pragma unroll
    for (int n = 0; n < 8; ++n) acc[m][n] = zero;

  int wave_m = wv >> 1, wave_n = wv & 1;
  int lane16 = lane & 15, kq4 = lane >> 4;
  int ra[4], rb[8];
#pragma unroll
  for (int m = 0; m < 4; ++m) {
    int r = wave_m * 64 + m * 16 + lane16;
    ra[m] = (r >> 1) * 128 + ((((kq4 + (r & 1) * 4)) ^ ((r >> 1) & 7)) << 4);
  }
#pragma unroll
  for (int n = 0; n < 8; ++n) {
    int rn = wave_n * 128 + n * 16 + lane16;
    rb[n] = (rn >> 1) * 128 + ((((kq4 + (rn & 1) * 4)) ^ ((rn >> 1) & 7)) << 4);
  }

  auto stage = [&](char* nb, int k0) {
    gl16(asrc[0] + k0, nb + dstA0);
    gl16(asrc[1] + k0, nb + dstA1);
    gl16(bsrc[0] + k0, nb + dstB);
    gl16(bsrc[1] + k0, nb + dstB + 1024);
    gl16(bsrc[2] + k0, nb + dstB + 2048);
    gl16(bsrc[3] + k0, nb + dstB + 3072);
  };
  auto compute = [&](const char* cb) {
    bf16x8 af[4], bfr[8];
#pragma unroll
    for (int m = 0; m < 4; ++m) af[m] = *reinterpret_cast<const bf16x8*>(cb + ra[m]);
#pragma unroll
    for (int n = 0; n < 8; ++n) bfr[n] = *reinterpret_cast<const bf16x8*>(cb + 8192 + rb[n]);
#pragma unroll
    for (int m = 0; m < 4; ++m)
#pragma unroll
      for (int n = 0; n < 8; ++n)
        acc[m][n] = __builtin_amdgcn_mfma_f32_16x16x32_bf16(af[m], bfr[n], acc[m][n], 0, 0, 0);
  };

  const int T = DIMD / 32;   // 16 steps
  stage(ldsb, 0);
  stage(ldsb + 24576, 32);
  for (int t = 0; t < T - 2; ++t) {
    char* cb = ldsb + (t & 1) * 24576;
    PIPE_WAIT6_BAR();          // tile t ready; tile t+1 stays in flight
    compute(cb);
    PIPE_POST_BAR();           // all waves done reading buf[t&1]
    stage(cb, (t + 2) * 32);
  }
  PIPE_WAIT6_BAR();
  compute(ldsb + ((T - 2) & 1) * 24576);
  PIPE_POST_BAR();
  PIPE_WAIT0_BAR();
  compute(ldsb + ((T - 1) & 1) * 24576);
  PIPE_POST_BAR();             // vmcnt==0 per wave; LDS reuse below is safe

  // epilogue: gelu -> bf16, two 64-row halves through LDS [64][264], uint4 store
  unsigned short* Ct = (unsigned short*)ldsb;
  const float* b1e = b1 + e * HIDN;
  float bias[8];
#pragma unroll
  for (int n = 0; n < 8; ++n) bias[n] = b1e[n0 + wave_n * 128 + n * 16 + lane16];
  for (int h = 0; h < 2; ++h) {
    if (wave_m == h) {
#pragma unroll
      for (int n = 0; n < 8; ++n) {
        int cl = wave_n * 128 + n * 16 + lane16;
#pragma unroll
        for (int m = 0; m < 4; ++m) {
#pragma unroll
          for (int q = 0; q < 4; ++q) {
            int rl = m * 16 + kq4 * 4 + q;
            float v = acc[m][n][q] + bias[n];
            float g = 0.5f * v * (1.f + erff(v * 0.70710678118654752f));
            Ct[rl * 264 + cl] = f2bf(g);
          }
        }
      }
    }
    __syncthreads();
#pragma unroll
    for (int j = 0; j < 8; ++j) {
      int u = tid + j * 256;
      int row = u >> 5, c8 = (u & 31) * 8;
      int r = m0 + h * 64 + row;
      if (r < cnt_e) {
        uint4 v = *reinterpret_cast<const uint4*>(Ct + row * 264 + c8);
        *reinterpret_cast<uint4*>(H + (size_t)(offe + r) * HIDN + n0 + c8) = v;
      }
    }
    __syncthreads();
  }
}

// ---------- GEMM2: Yw[a] = tw[a]*(H @ W2 + b2); counted-vmcnt dbuf BK=32 (round-8 proven) ----------
__global__ __launch_bounds__(256) void gemm2_kernel(
    const unsigned short* __restrict__ H,
    const unsigned short* __restrict__ w2t,   // [E][512][2048]
    const float* __restrict__ b2,
    const int* __restrict__ off,
    const int* __restrict__ list,
    const float* __restrict__ tw,
    float* __restrict__ Yw) {
  int e = blockIdx.x;
  int offe = off[e];
  int cnt_e = off[e + 1] - offe;
  int n0 = blockIdx.y * 128;
  int m0 = blockIdx.z * 128;
  if (m0 >= cnt_e) return;

  __shared__ char ldsb[32768];

  int tid = threadIdx.x, wv = tid >> 6, lane = tid & 63;
  int rp = lane >> 3, sl = lane & 7;
  int sx = sl ^ rp;
  int rowadd = rp * 2 + (sx >> 2);
  int kq = sx & 3;

  const unsigned short* w2e = w2t + (size_t)e * DIMD * HIDN;
  const unsigned short* asrc[2];
  const unsigned short* bsrc[2];
#pragma unroll
  for (int i = 0; i < 2; ++i) {
    int r = wv * 32 + i * 16 + rowadd;
    int rowa = offe + m0 + r;
    if (rowa > NASG - 1) rowa = NASG - 1;    // pad rows: clamp (values discarded)
    asrc[i] = H + (size_t)rowa * HIDN + kq * 8;
    bsrc[i] = w2e + (size_t)(n0 + r) * HIDN + kq * 8;
  }
  int dstA0 = wv * 2048;
  int dstA1 = wv * 2048 + 1024;

  f32x4 zero = {0.f, 0.f, 0.f, 0.f};
  f32x4 acc[4][4];
#pragma unroll
  for (int m = 0; m < 4; ++m)
#pragma unroll
    for (int n = 0; n < 4; ++n) acc[m][n] = zero;

  int wave_m = wv >> 1, wave_n = wv & 1;
  int lane16 = lane & 15, kq4 = lane >> 4;
  int ra[4], rb[4];
#pragma unroll
  for (int m = 0; m < 4; ++m) {
    int r = wave_m * 64 + m * 16 + lane16;
    ra[m] = (r >> 1) * 128 + ((((kq4 + (r & 1) * 4)) ^ ((r >> 1) & 7)) << 4);
    int rn = wave_n * 64 + m * 16 + lane16;
    rb[m] = (rn >> 1) * 128 + ((((kq4 + (rn & 1) * 4)) ^ ((rn >> 1) & 7)) << 4);
  }

  auto stage = [&](char* nb, int k0) {
    gl16(asrc[0] + k0, nb + dstA0);
    gl16(asrc[1] + k0, nb + dstA1);
    gl16(bsrc[0] + k0, nb + 8192 + dstA0);
    gl16(bsrc[1] + k0, nb + 8192 + dstA1);
  };
  auto compute = [&](const char* cb) {
    bf16x8 af[4], bfr[4];
#pragma unroll
    for (int m = 0; m < 4; ++m) af[m] = *reinterpret_cast<const bf16x8*>(cb + ra[m]);
#pragma unroll
    for (int n = 0; n < 4; ++n) bfr[n] = *reinterpret_cast<const bf16x8*>(cb + 8192 + rb[n]);
#pragma unroll
    for (int m = 0; m < 4; ++m)
#pragma unroll
      for (int n = 0; n < 4; ++n)
        acc[m][n] = __builtin_amdgcn_mfma_f32_16x16x32_bf16(af[m], bfr[n], acc[m][n], 0, 0, 0);
  };

  const int T = HIDN / 32;   // 64 steps
  stage(ldsb, 0);
  stage(ldsb + 16384, 32);
  for (int t = 0; t < T - 2; ++t) {
    char* cb = ldsb + (t & 1) * 16384;
    PIPE_WAIT4_BAR();
    compute(cb);
    PIPE_POST_BAR();
    stage(cb, (t + 2) * 32);
  }
  PIPE_WAIT4_BAR();
  compute(ldsb + ((T - 2) & 1) * 16384);
  PIPE_POST_BAR();
  PIPE_WAIT0_BAR();
  compute(ldsb + ((T - 1) & 1) * 16384);
  PIPE_POST_BAR();

  const float* b2e = b2 + e * DIMD;
  float bias[4];
#pragma unroll
  for (int n = 0; n < 4; ++n) bias[n] = b2e[n0 + wave_n * 64 + n * 16 + lane16];
#pragma unroll
  for (int m = 0; m < 4; ++m) {
#pragma unroll
    for (int q = 0; q < 4; ++q) {
      int r = m0 + wave_m * 64 + m * 16 + kq4 * 4 + q;
      if (r < cnt_e) {
        int a = list[offe + r];
        float w = tw[a];
        float* yrow = Yw + (size_t)a * DIMD;
#pragma unroll
        for (int n = 0; n < 4; ++n) {
          int col = n0 + wave_n * 64 + n * 16 + lane16;
          yrow[col] = w * (acc[m][n][q] + bias[n]);
        }
      }
    }
  }
}

// ---------- combine: out[n] = Yw[2n] + Yw[2n+1] ----------
__global__ __launch_bounds__(256) void combine_kernel(const float* __restrict__ Yw,
                                                      float* __restrict__ out) {
  int i = (blockIdx.x * 256 + threadIdx.x) * 4;
  int n = i >> 9;
  int d = i & 511;
  float4 a = *reinterpret_cast<const float4*>(Yw + (size_t)(2 * n) * DIMD + d);
  float4 b = *reinterpret_cast<const float4*>(Yw + (size_t)(2 * n + 1) * DIMD + d);
  float4 o;
  o.x = a.x + b.x; o.y = a.y + b.y; o.z = a.z + b.z; o.w = a.w + b.w;
  *reinterpret_cast<float4*>(out + i) = o;
}

extern "C" void kernel_launch(void* const* d_in, const int* in_sizes, int n_in,
                              void* d_out, int out_size, void* d_ws, size_t ws_size,
                              hipStream_t stream) {
  const float* x  = (const float*)d_in[0];
  const float* Wr = (const float*)d_in[1];
  const float* br = (const float*)d_in[2];
  const float* W1 = (const float*)d_in[3];
  const float* b1 = (const float*)d_in[4];
  const float* W2 = (const float*)d_in[5];
  const float* b2 = (const float*)d_in[6];
  float* out = (float*)d_out;

  char* ws = (char*)d_ws;
  unsigned short* xb  = (unsigned short*)ws;  ws += (size_t)NTOK * DIMD * 2;
  unsigned short* w1t = (unsigned short*)ws;  ws += (size_t)NEXP * HIDN * DIMD * 2;
  unsigned short* w2t = (unsigned short*)ws;  ws += (size_t)NEXP * DIMD * HIDN * 2;
  unsigned short* H   = (unsigned short*)ws;  ws += (size_t)NASG * HIDN * 2;
  float* Yw = (float*)ws;                     ws += (size_t)NASG * DIMD * 4;
  float* tw = (float*)ws;                     ws += (size_t)NASG * 4;
  int* tidx = (int*)ws;                       ws += (size_t)NASG * 4;
  int* list = (int*)ws;                       ws += (size_t)NASG * 4;
  int* offp = (int*)ws;                       // off[9]

  transpose_both_kernel<<<dim3(32, 8, 16), 256, 0, stream>>>(W1, W2, w1t, w2t);
  router_kernel<<<NTOK / 4, 256, 0, stream>>>(x, Wr, br, tidx, tw, xb);
  route_pack_kernel<<<1, 1024, 0, stream>>>(tidx, offp, list, out + (size_t)NTOK * DIMD);
  // expert = blockIdx.x -> grid-linear %8 == expert -> XCD-pinned weight panels
  gemm1_kernel<<<dim3(NEXP, HIDN / 256, NASG / 128), 256, 0, stream>>>(xb, w1t, b1, offp, list, H);
  gemm2_kernel<<<dim3(NEXP, DIMD / 128, NASG / 128), 256, 0, stream>>>(H, w2t, b2, offp, list, tw, Yw);
  combine_kernel<<<2048, 256, 0, stream>>>(Yw, out);
}

// Round 13
// 127.195 us; speedup vs baseline: 1.8704x; 1.8704x over previous
//
#include <hip/hip_runtime.h>
#include <hip/hip_bf16.h>

#define DIMD 512
#define NEXP 8
#define HIDN 2048
#define NTOK 4096
#define NASG 8192

typedef short bf16x8 __attribute__((ext_vector_type(8)));
typedef float f32x4 __attribute__((ext_vector_type(4)));

__device__ inline unsigned short f2bf(float f) {
  __hip_bfloat16 h = __float2bfloat16(f);
  return __builtin_bit_cast(unsigned short, h);
}

__device__ inline void gl16(const void* g, void* l) {
  __builtin_amdgcn_global_load_lds(
      (const __attribute__((address_space(1))) unsigned int*)g,
      (__attribute__((address_space(3))) unsigned int*)l, 16, 0, 0);
}

// Counted-vmcnt barrier discipline: wait only the OLDER stage's loads.
#define PIPE_WAIT4_BAR() do { \
  asm volatile("s_waitcnt vmcnt(4)" ::: "memory"); \
  __builtin_amdgcn_s_barrier(); \
  __builtin_amdgcn_sched_barrier(0); } while (0)
#define PIPE_WAIT0_BAR() do { \
  asm volatile("s_waitcnt vmcnt(0)" ::: "memory"); \
  __builtin_amdgcn_s_barrier(); \
  __builtin_amdgcn_sched_barrier(0); } while (0)
#define PIPE_POST_BAR() do { \
  asm volatile("" ::: "memory"); \
  __builtin_amdgcn_sched_barrier(0); \
  __builtin_amdgcn_s_barrier(); } while (0)

// ---------- fused prep: W transposes (blocks 0..4095) + router (blocks 4096..5119) ----------
__global__ __launch_bounds__(256) void prep_kernel(
    const float* __restrict__ W1, const float* __restrict__ W2,
    unsigned short* __restrict__ w1t, unsigned short* __restrict__ w2t,
    const float* __restrict__ x, const float* __restrict__ Wr,
    const float* __restrict__ br,
    int* __restrict__ tidx, float* __restrict__ tw,
    unsigned short* __restrict__ xb) {
  int b = blockIdx.x;
  if (b < 4096) {
    // ----- transpose part: [E][R][C] fp32 -> [E][C][R] bf16 -----
    __shared__ float tile[64][65];
    int bx = b & 31, by = (b >> 5) & 7, z = b >> 8;
    int e = z & 7;
    const float* src; unsigned short* dst; int R, C, r0, c0;
    if (z < 8) { src = W1; dst = w1t; R = DIMD; C = HIDN; c0 = bx * 64; r0 = by * 64; }
    else       { src = W2; dst = w2t; R = HIDN; C = DIMD; r0 = bx * 64; c0 = by * 64; }
    const float* s = src + (size_t)e * R * C;
    unsigned short* d = dst + (size_t)e * R * C;
    for (int i = threadIdx.x; i < 1024; i += 256) {
      int r = i >> 4, c4 = (i & 15) * 4;
      float4 v = *reinterpret_cast<const float4*>(s + (size_t)(r0 + r) * C + (c0 + c4));
      tile[r][c4] = v.x; tile[r][c4 + 1] = v.y; tile[r][c4 + 2] = v.z; tile[r][c4 + 3] = v.w;
    }
    __syncthreads();
    for (int i = threadIdx.x; i < 1024; i += 256) {
      int c = i >> 4;
      int r = (i & 15) * 4;
      unsigned u0 = (unsigned)f2bf(tile[r][c]) | ((unsigned)f2bf(tile[r + 1][c]) << 16);
      unsigned u1 = (unsigned)f2bf(tile[r + 2][c]) | ((unsigned)f2bf(tile[r + 3][c]) << 16);
      *reinterpret_cast<uint2*>(d + (size_t)(c0 + c) * R + (r0 + r)) = make_uint2(u0, u1);
    }
    return;
  }
  // ----- router part: logits, softmax, top-2, renorm; emits x in bf16. NO atomics. -----
  int lane = threadIdx.x & 63;
  int n = (b - 4096) * 4 + (threadIdx.x >> 6);
  const float* xr = x + (size_t)n * DIMD;
  unsigned short* xbr = xb + (size_t)n * DIMD;
  float acc[NEXP];
#pragma unroll
  for (int e = 0; e < NEXP; ++e) acc[e] = 0.f;
#pragma unroll
  for (int it = 0; it < 2; ++it) {
    int d0 = it * 256 + lane * 4;
    float4 xv = *reinterpret_cast<const float4*>(xr + d0);
    unsigned p0 = (unsigned)f2bf(xv.x) | ((unsigned)f2bf(xv.y) << 16);
    unsigned p1 = (unsigned)f2bf(xv.z) | ((unsigned)f2bf(xv.w) << 16);
    *reinterpret_cast<uint2*>(xbr + d0) = make_uint2(p0, p1);
    const float* wr = Wr + (size_t)d0 * NEXP;
#pragma unroll
    for (int j = 0; j < 4; ++j) {
      float xj = (&xv.x)[j];
#pragma unroll
      for (int e = 0; e < NEXP; ++e) acc[e] += xj * wr[j * NEXP + e];
    }
  }
#pragma unroll
  for (int e = 0; e < NEXP; ++e) {
    float v = acc[e];
#pragma unroll
    for (int off = 32; off > 0; off >>= 1) v += __shfl_xor(v, off, 64);
    acc[e] = v + br[e];
  }
  if (lane == 0) {
    float m = acc[0];
    for (int e = 1; e < NEXP; ++e) m = fmaxf(m, acc[e]);
    float p[NEXP], s = 0.f;
    for (int e = 0; e < NEXP; ++e) { p[e] = expf(acc[e] - m); s += p[e]; }
    float inv = 1.f / s;
    for (int e = 0; e < NEXP; ++e) p[e] *= inv;
    int i0 = 0; float p0 = p[0];
    for (int e = 1; e < NEXP; ++e) if (p[e] > p0) { p0 = p[e]; i0 = e; }
    int i1 = (i0 == 0) ? 1 : 0; float p1 = p[i1];
    for (int e = 0; e < NEXP; ++e) if (e != i0 && p[e] > p1) { p1 = p[e]; i1 = e; }
    // reference renormalizes by softmax over the top-2 *probabilities*
    float t = expf(p1 - p0);
    float w0 = 1.f / (1.f + t);
    tidx[2 * n] = i0; tidx[2 * n + 1] = i1;
    tw[2 * n] = w0; tw[2 * n + 1] = t * w0;
  }
}

// ---------- route_pack: counts + offsets + stable scatter + lb tail, single block ----------
__global__ __launch_bounds__(1024) void route_pack_kernel(const int* __restrict__ tidx,
                                                          int* __restrict__ off,
                                                          int* __restrict__ list,
                                                          float* __restrict__ out_tail) {
  int tid = threadIdx.x;
  int wv = tid >> 6, lane = tid & 63;

  int ids[8];
#pragma unroll
  for (int j = 0; j < 8; ++j) ids[j] = tidx[tid * 8 + j];

  int c[NEXP];
#pragma unroll
  for (int e = 0; e < NEXP; ++e) c[e] = 0;
#pragma unroll
  for (int j = 0; j < 8; ++j)
#pragma unroll
    for (int e = 0; e < NEXP; ++e) c[e] += (ids[j] == e) ? 1 : 0;

  int inc[NEXP];
#pragma unroll
  for (int e = 0; e < NEXP; ++e) {
    int v = c[e];
#pragma unroll
    for (int d = 1; d < 64; d <<= 1) {
      int t = __shfl_up(v, d, 64);
      if (lane >= d) v += t;
    }
    inc[e] = v;
  }

  __shared__ int wtot[NEXP][16];
  __shared__ int wbase[NEXP][16];
  __shared__ int ebase[NEXP];
  if (lane == 63) {
#pragma unroll
    for (int e = 0; e < NEXP; ++e) wtot[e][wv] = inc[e];
  }
  __syncthreads();
  if (tid == 0) {
    int o = 0;
    float lb = 0.f;
    for (int e = 0; e < NEXP; ++e) {
      int s = 0;
      for (int w = 0; w < 16; ++w) { wbase[e][w] = s; s += wtot[e][w]; }
      ebase[e] = o;
      off[e] = o;
      o += s;
      float l = (float)s / (float)NASG;
      out_tail[1 + e] = l;
      float dd = l - 0.125f;
      lb += dd * dd;
    }
    off[NEXP] = o;
    out_tail[0] = lb;
  }
  __syncthreads();

  int pos[NEXP];
#pragma unroll
  for (int e = 0; e < NEXP; ++e)
    pos[e] = ebase[e] + wbase[e][wv] + (inc[e] - c[e]);

#pragma unroll
  for (int j = 0; j < 8; ++j) {
    int e = ids[j];
    int p = 0;
#pragma unroll
    for (int k = 0; k < NEXP; ++k)
      if (e == k) { p = pos[k]; pos[k] = p + 1; }
    list[p] = tid * 8 + j;
  }
}

// ===== BK=32 tile: row-pair packed LDS, 2-way-free swizzle (round-8 proven) =====
// byte(r, kq) = (r>>1)*128 + (((kq + (r&1)*4) ^ ((r>>1)&7)) << 4)
// Staged linearly by gl16 from pre-swizzled per-lane global sources.

// ---------- GEMM1: H = gelu(Xg @ W1 + b1); counted-vmcnt dbuf BK=32 ----------
__global__ __launch_bounds__(256) void gemm1_kernel(
    const unsigned short* __restrict__ xb,
    const unsigned short* __restrict__ w1t,   // [E][2048][512]
    const float* __restrict__ b1,
    const int* __restrict__ off,
    const int* __restrict__ list,
    unsigned short* __restrict__ H) {
  int e = blockIdx.x;                        // linear%8 == e -> expert pinned to one XCD
  int offe = off[e];
  int cnt_e = off[e + 1] - offe;
  int n0 = blockIdx.y * 128;
  int m0 = blockIdx.z * 128;
  if (m0 >= cnt_e) return;

  __shared__ char ldsb[36864];   // 2 x (A 8K | B 8K) = 32K; epilogue uses 34816

  int tid = threadIdx.x, wv = tid >> 6, lane = tid & 63;
  int rp = lane >> 3, sl = lane & 7;
  int sx = sl ^ rp;
  int rowadd = rp * 2 + (sx >> 2);
  int kq = sx & 3;

  const unsigned short* w1e = w1t + (size_t)e * HIDN * DIMD;
  const unsigned short* asrc[2];
  const unsigned short* bsrc[2];
#pragma unroll
  for (int i = 0; i < 2; ++i) {
    int r = wv * 32 + i * 16 + rowadd;
    int rr = m0 + r;
    int tok = 0;
    if (rr < cnt_e) tok = list[offe + rr] >> 1;
    asrc[i] = xb + (size_t)tok * DIMD + kq * 8;
    bsrc[i] = w1e + (size_t)(n0 + r) * DIMD + kq * 8;
  }
  int dstA0 = wv * 2048;
  int dstA1 = wv * 2048 + 1024;

  f32x4 zero = {0.f, 0.f, 0.f, 0.f};
  f32x4 acc[4][4];
#pragma unroll
  for (int m = 0; m < 4; ++m)
#pragma unroll
    for (int n = 0; n < 4; ++n) acc[m][n] = zero;

  int wave_m = wv >> 1, wave_n = wv & 1;
  int lane16 = lane & 15, kq4 = lane >> 4;
  int ra[4], rb[4];
#pragma unroll
  for (int m = 0; m < 4; ++m) {
    int r = wave_m * 64 + m * 16 + lane16;
    ra[m] = (r >> 1) * 128 + ((((kq4 + (r & 1) * 4)) ^ ((r >> 1) & 7)) << 4);
    int rn = wave_n * 64 + m * 16 + lane16;
    rb[m] = (rn >> 1) * 128 + ((((kq4 + (rn & 1) * 4)) ^ ((rn >> 1) & 7)) << 4);
  }

  auto stage = [&](char* nb, int k0) {
    gl16(asrc[0] + k0, nb + dstA0);
    gl16(asrc[1] + k0, nb + dstA1);
    gl16(bsrc[0] + k0, nb + 8192 + dstA0);
    gl16(bsrc[1] + k0, nb + 8192 + dstA1);
  };
  auto compute = [&](const char* cb) {
    bf16x8 af[4], bfr[4];
#pragma unroll
    for (int m = 0; m < 4; ++m) af[m] = *reinterpret_cast<const bf16x8*>(cb + ra[m]);
#pragma unroll
    for (int n = 0; n < 4; ++n) bfr[n] = *reinterpret_cast<const bf16x8*>(cb + 8192 + rb[n]);
#pragma unroll
    for (int m = 0; m < 4; ++m)
#pragma unroll
      for (int n = 0; n < 4; ++n)
        acc[m][n] = __builtin_amdgcn_mfma_f32_16x16x32_bf16(af[m], bfr[n], acc[m][n], 0, 0, 0);
  };

  const int T = DIMD / 32;   // 16 steps
  stage(ldsb, 0);
  stage(ldsb + 16384, 32);
  for (int t = 0; t < T - 2; ++t) {
    char* cb = ldsb + (t & 1) * 16384;
    PIPE_WAIT4_BAR();          // tile t ready; tile t+1 stays in flight
    compute(cb);
    PIPE_POST_BAR();           // all waves done reading buf[t&1]
    stage(cb, (t + 2) * 32);   // re-stage same buffer with tile t+2
  }
  PIPE_WAIT4_BAR();
  compute(ldsb + ((T - 2) & 1) * 16384);
  PIPE_POST_BAR();
  PIPE_WAIT0_BAR();
  compute(ldsb + ((T - 1) & 1) * 16384);
  PIPE_POST_BAR();             // vmcnt==0 per wave; LDS reuse below is safe

  // epilogue: gelu -> bf16 C-tile in LDS (stride 136 shorts), coalesced uint4 store
  unsigned short* Ct = (unsigned short*)ldsb;
  const float* b1e = b1 + e * HIDN;
#pragma unroll
  for (int n = 0; n < 4; ++n) {
    int cl = wave_n * 64 + n * 16 + lane16;
    float bias = b1e[n0 + cl];
#pragma unroll
    for (int m = 0; m < 4; ++m) {
#pragma unroll
      for (int q = 0; q < 4; ++q) {
        int rl = wave_m * 64 + m * 16 + kq4 * 4 + q;
        float v = acc[m][n][q] + bias;
        float g = 0.5f * v * (1.f + erff(v * 0.70710678118654752f));
        Ct[rl * 136 + cl] = f2bf(g);
      }
    }
  }
  __syncthreads();
  for (int u = tid; u < 2048; u += 256) {
    int rl = u >> 4, c8 = (u & 15) * 8;
    int r = m0 + rl;
    if (r < cnt_e) {
      uint4 v = *reinterpret_cast<const uint4*>(Ct + rl * 136 + c8);
      *reinterpret_cast<uint4*>(H + (size_t)(offe + r) * HIDN + n0 + c8) = v;
    }
  }
}

// ---------- GEMM2: out[tok] += tw[a]*(H @ W2 + b2) via atomics (2 adds/elem, deterministic) ----------
__global__ __launch_bounds__(256) void gemm2_kernel(
    const unsigned short* __restrict__ H,
    const unsigned short* __restrict__ w2t,   // [E][512][2048]
    const float* __restrict__ b2,
    const int* __restrict__ off,
    const int* __restrict__ list,
    const float* __restrict__ tw,
    float* __restrict__ out) {
  int e = blockIdx.x;
  int offe = off[e];
  int cnt_e = off[e + 1] - offe;
  int n0 = blockIdx.y * 128;
  int m0 = blockIdx.z * 128;
  if (m0 >= cnt_e) return;

  __shared__ char ldsb[32768];

  int tid = threadIdx.x, wv = tid >> 6, lane = tid & 63;
  int rp = lane >> 3, sl = lane & 7;
  int sx = sl ^ rp;
  int rowadd = rp * 2 + (sx >> 2);
  int kq = sx & 3;

  const unsigned short* w2e = w2t + (size_t)e * DIMD * HIDN;
  const unsigned short* asrc[2];
  const unsigned short* bsrc[2];
#pragma unroll
  for (int i = 0; i < 2; ++i) {
    int r = wv * 32 + i * 16 + rowadd;
    int rowa = offe + m0 + r;
    if (rowa > NASG - 1) rowa = NASG - 1;    // pad rows: clamp (values discarded)
    asrc[i] = H + (size_t)rowa * HIDN + kq * 8;
    bsrc[i] = w2e + (size_t)(n0 + r) * HIDN + kq * 8;
  }
  int dstA0 = wv * 2048;
  int dstA1 = wv * 2048 + 1024;

  f32x4 zero = {0.f, 0.f, 0.f, 0.f};
  f32x4 acc[4][4];
#pragma unroll
  for (int m = 0; m < 4; ++m)
#pragma unroll
    for (int n = 0; n < 4; ++n) acc[m][n] = zero;

  int wave_m = wv >> 1, wave_n = wv & 1;
  int lane16 = lane & 15, kq4 = lane >> 4;
  int ra[4], rb[4];
#pragma unroll
  for (int m = 0; m < 4; ++m) {
    int r = wave_m * 64 + m * 16 + lane16;
    ra[m] = (r >> 1) * 128 + ((((kq4 + (r & 1) * 4)) ^ ((r >> 1) & 7)) << 4);
    int rn = wave_n * 64 + m * 16 + lane16;
    rb[m] = (rn >> 1) * 128 + ((((kq4 + (rn & 1) * 4)) ^ ((rn >> 1) & 7)) << 4);
  }

  auto stage = [&](char* nb, int k0) {
    gl16(asrc[0] + k0, nb + dstA0);
    gl16(asrc[1] + k0, nb + dstA1);
    gl16(bsrc[0] + k0, nb + 8192 + dstA0);
    gl16(bsrc[1] + k0, nb + 8192 + dstA1);
  };
  auto compute = [&](const char* cb) {
    bf16x8 af[4], bfr[4];
#pragma unroll
    for (int m = 0; m < 4; ++m) af[m] = *reinterpret_cast<const bf16x8*>(cb + ra[m]);
#pragma unroll
    for (int n = 0; n < 4; ++n) bfr[n] = *reinterpret_cast<const bf16x8*>(cb + 8192 + rb[n]);
#pragma unroll
    for (int m = 0; m < 4; ++m)
#pragma unroll
      for (int n = 0; n < 4; ++n)
        acc[m][n] = __builtin_amdgcn_mfma_f32_16x16x32_bf16(af[m], bfr[n], acc[m][n], 0, 0, 0);
  };

  const int T = HIDN / 32;   // 64 steps
  stage(ldsb, 0);
  stage(ldsb + 16384, 32);
  for (int t = 0; t < T - 2; ++t) {
    char* cb = ldsb + (t & 1) * 16384;
    PIPE_WAIT4_BAR();
    compute(cb);
    PIPE_POST_BAR();
    stage(cb, (t + 2) * 32);
  }
  PIPE_WAIT4_BAR();
  compute(ldsb + ((T - 2) & 1) * 16384);
  PIPE_POST_BAR();
  PIPE_WAIT0_BAR();
  compute(ldsb + ((T - 1) & 1) * 16384);
  PIPE_POST_BAR();

  const float* b2e = b2 + e * DIMD;
  float bias[4];
#pragma unroll
  for (int n = 0; n < 4; ++n) bias[n] = b2e[n0 + wave_n * 64 + n * 16 + lane16];
#pragma unroll
  for (int m = 0; m < 4; ++m) {
#pragma unroll
    for (int q = 0; q < 4; ++q) {
      int r = m0 + wave_m * 64 + m * 16 + kq4 * 4 + q;
      if (r < cnt_e) {
        int a = list[offe + r];
        float w = tw[a];
        float* orow = out + (size_t)(a >> 1) * DIMD;
#pragma unroll
        for (int n = 0; n < 4; ++n) {
          int col = n0 + wave_n * 64 + n * 16 + lane16;
          atomicAdd(&orow[col], w * (acc[m][n][q] + bias[n]));
        }
      }
    }
  }
}

extern "C" void kernel_launch(void* const* d_in, const int* in_sizes, int n_in,
                              void* d_out, int out_size, void* d_ws, size_t ws_size,
                              hipStream_t stream) {
  const float* x  = (const float*)d_in[0];
  const float* Wr = (const float*)d_in[1];
  const float* br = (const float*)d_in[2];
  const float* W1 = (const float*)d_in[3];
  const float* b1 = (const float*)d_in[4];
  const float* W2 = (const float*)d_in[5];
  const float* b2 = (const float*)d_in[6];
  float* out = (float*)d_out;

  char* ws = (char*)d_ws;
  unsigned short* xb  = (unsigned short*)ws;  ws += (size_t)NTOK * DIMD * 2;
  unsigned short* w1t = (unsigned short*)ws;  ws += (size_t)NEXP * HIDN * DIMD * 2;
  unsigned short* w2t = (unsigned short*)ws;  ws += (size_t)NEXP * DIMD * HIDN * 2;
  unsigned short* H   = (unsigned short*)ws;  ws += (size_t)NASG * HIDN * 2;
  float* tw = (float*)ws;                     ws += (size_t)NASG * 4;
  int* tidx = (int*)ws;                       ws += (size_t)NASG * 4;
  int* list = (int*)ws;                       ws += (size_t)NASG * 4;
  int* offp = (int*)ws;                       // off[9]

  // token-output region zeroed for the deterministic 2-contribution atomic combine
  hipMemsetAsync(out, 0, (size_t)NTOK * DIMD * 4, stream);
  prep_kernel<<<4096 + NTOK / 4, 256, 0, stream>>>(W1, W2, w1t, w2t, x, Wr, br, tidx, tw, xb);
  route_pack_kernel<<<1, 1024, 0, stream>>>(tidx, offp, list, out + (size_t)NTOK * DIMD);
  // expert = blockIdx.x -> grid-linear %8 == expert -> XCD-pinned weight panels
  gemm1_kernel<<<dim3(NEXP, HIDN / 128, NASG / 128), 256, 0, stream>>>(xb, w1t, b1, offp, list, H);
  gemm2_kernel<<<dim3(NEXP, DIMD / 128, NASG / 128), 256, 0, stream>>>(H, w2t, b2, offp, list, tw, out);
}

// Round 14
// 118.513 us; speedup vs baseline: 2.0074x; 1.0733x over previous
//
#include <hip/hip_runtime.h>
#include <hip/hip_bf16.h>

#define DIMD 512
#define NEXP 8
#define HIDN 2048
#define NTOK 4096
#define NASG 8192

typedef short bf16x8 __attribute__((ext_vector_type(8)));
typedef float f32x4 __attribute__((ext_vector_type(4)));

__device__ inline unsigned short f2bf(float f) {
  __hip_bfloat16 h = __float2bfloat16(f);
  return __builtin_bit_cast(unsigned short, h);
}

__device__ inline void gl16(const void* g, void* l) {
  __builtin_amdgcn_global_load_lds(
      (const __attribute__((address_space(1))) unsigned int*)g,
      (__attribute__((address_space(3))) unsigned int*)l, 16, 0, 0);
}

// Counted-vmcnt barrier discipline: wait only the OLDER stage's loads.
#define PIPE_WAIT4_BAR() do { \
  asm volatile("s_waitcnt vmcnt(4)" ::: "memory"); \
  __builtin_amdgcn_s_barrier(); \
  __builtin_amdgcn_sched_barrier(0); } while (0)
#define PIPE_WAIT0_BAR() do { \
  asm volatile("s_waitcnt vmcnt(0)" ::: "memory"); \
  __builtin_amdgcn_s_barrier(); \
  __builtin_amdgcn_sched_barrier(0); } while (0)
#define PIPE_POST_BAR() do { \
  asm volatile("" ::: "memory"); \
  __builtin_amdgcn_sched_barrier(0); \
  __builtin_amdgcn_s_barrier(); } while (0)

// ---------- both W transposes in one launch: [E][R][C] fp32 -> [E][C][R] bf16 ----------
__global__ __launch_bounds__(256) void transpose_both_kernel(
    const float* __restrict__ W1, const float* __restrict__ W2,
    unsigned short* __restrict__ w1t, unsigned short* __restrict__ w2t) {
  __shared__ float tile[64][65];
  int z = blockIdx.z;
  int e = z & 7;
  const float* src; unsigned short* dst; int R, C, r0, c0;
  if (z < 8) { src = W1; dst = w1t; R = DIMD; C = HIDN; c0 = blockIdx.x * 64; r0 = blockIdx.y * 64; }
  else       { src = W2; dst = w2t; R = HIDN; C = DIMD; r0 = blockIdx.x * 64; c0 = blockIdx.y * 64; }
  const float* s = src + (size_t)e * R * C;
  unsigned short* d = dst + (size_t)e * R * C;
  // float4 coalesced reads
  for (int i = threadIdx.x; i < 1024; i += 256) {
    int r = i >> 4, c4 = (i & 15) * 4;
    float4 v = *reinterpret_cast<const float4*>(s + (size_t)(r0 + r) * C + (c0 + c4));
    tile[r][c4] = v.x; tile[r][c4 + 1] = v.y; tile[r][c4 + 2] = v.z; tile[r][c4 + 3] = v.w;
  }
  __syncthreads();
  // uint2 packed writes (4 consecutive r per thread)
  for (int i = threadIdx.x; i < 1024; i += 256) {
    int c = i >> 4;
    int r = (i & 15) * 4;
    unsigned u0 = (unsigned)f2bf(tile[r][c]) | ((unsigned)f2bf(tile[r + 1][c]) << 16);
    unsigned u1 = (unsigned)f2bf(tile[r + 2][c]) | ((unsigned)f2bf(tile[r + 3][c]) << 16);
    *reinterpret_cast<uint2*>(d + (size_t)(c0 + c) * R + (r0 + r)) = make_uint2(u0, u1);
  }
}

// ---------- router: logits, softmax, top-2, renorm; emits x in bf16. NO atomics. ----------
__global__ __launch_bounds__(256) void router_kernel(const float* __restrict__ x,
                                                     const float* __restrict__ Wr,
                                                     const float* __restrict__ br,
                                                     int* __restrict__ tidx,
                                                     float* __restrict__ tw,
                                                     unsigned short* __restrict__ xb) {
  int lane = threadIdx.x & 63;
  int n = blockIdx.x * 4 + (threadIdx.x >> 6);
  const float* xr = x + (size_t)n * DIMD;
  unsigned short* xbr = xb + (size_t)n * DIMD;
  float acc[NEXP];
#pragma unroll
  for (int e = 0; e < NEXP; ++e) acc[e] = 0.f;
#pragma unroll
  for (int it = 0; it < 2; ++it) {
    int d0 = it * 256 + lane * 4;
    float4 xv = *reinterpret_cast<const float4*>(xr + d0);
    unsigned p0 = (unsigned)f2bf(xv.x) | ((unsigned)f2bf(xv.y) << 16);
    unsigned p1 = (unsigned)f2bf(xv.z) | ((unsigned)f2bf(xv.w) << 16);
    *reinterpret_cast<uint2*>(xbr + d0) = make_uint2(p0, p1);
    const float* wr = Wr + (size_t)d0 * NEXP;
#pragma unroll
    for (int j = 0; j < 4; ++j) {
      float xj = (&xv.x)[j];
#pragma unroll
      for (int e = 0; e < NEXP; ++e) acc[e] += xj * wr[j * NEXP + e];
    }
  }
#pragma unroll
  for (int e = 0; e < NEXP; ++e) {
    float v = acc[e];
#pragma unroll
    for (int off = 32; off > 0; off >>= 1) v += __shfl_xor(v, off, 64);
    acc[e] = v + br[e];
  }
  if (lane == 0) {
    float m = acc[0];
    for (int e = 1; e < NEXP; ++e) m = fmaxf(m, acc[e]);
    float p[NEXP], s = 0.f;
    for (int e = 0; e < NEXP; ++e) { p[e] = expf(acc[e] - m); s += p[e]; }
    float inv = 1.f / s;
    for (int e = 0; e < NEXP; ++e) p[e] *= inv;
    int i0 = 0; float p0 = p[0];
    for (int e = 1; e < NEXP; ++e) if (p[e] > p0) { p0 = p[e]; i0 = e; }
    int i1 = (i0 == 0) ? 1 : 0; float p1 = p[i1];
    for (int e = 0; e < NEXP; ++e) if (e != i0 && p[e] > p1) { p1 = p[e]; i1 = e; }
    // reference renormalizes by softmax over the top-2 *probabilities*
    float t = expf(p1 - p0);
    float w0 = 1.f / (1.f + t);
    tidx[2 * n] = i0; tidx[2 * n + 1] = i1;
    tw[2 * n] = w0; tw[2 * n + 1] = t * w0;
  }
}

// ---------- route_pack: counts + offsets + stable scatter + lb tail, single block ----------
__global__ __launch_bounds__(1024) void route_pack_kernel(const int* __restrict__ tidx,
                                                          int* __restrict__ off,
                                                          int* __restrict__ list,
                                                          float* __restrict__ out_tail) {
  int tid = threadIdx.x;
  int wv = tid >> 6, lane = tid & 63;

  int ids[8];
#pragma unroll
  for (int j = 0; j < 8; ++j) ids[j] = tidx[tid * 8 + j];

  int c[NEXP];
#pragma unroll
  for (int e = 0; e < NEXP; ++e) c[e] = 0;
#pragma unroll
  for (int j = 0; j < 8; ++j)
#pragma unroll
    for (int e = 0; e < NEXP; ++e) c[e] += (ids[j] == e) ? 1 : 0;

  int inc[NEXP];
#pragma unroll
  for (int e = 0; e < NEXP; ++e) {
    int v = c[e];
#pragma unroll
    for (int d = 1; d < 64; d <<= 1) {
      int t = __shfl_up(v, d, 64);
      if (lane >= d) v += t;
    }
    inc[e] = v;
  }

  __shared__ int wtot[NEXP][16];
  __shared__ int wbase[NEXP][16];
  __shared__ int ebase[NEXP];
  if (lane == 63) {
#pragma unroll
    for (int e = 0; e < NEXP; ++e) wtot[e][wv] = inc[e];
  }
  __syncthreads();
  if (tid == 0) {
    int o = 0;
    float lb = 0.f;
    for (int e = 0; e < NEXP; ++e) {
      int s = 0;
      for (int w = 0; w < 16; ++w) { wbase[e][w] = s; s += wtot[e][w]; }
      ebase[e] = o;
      off[e] = o;
      o += s;
      float l = (float)s / (float)NASG;
      out_tail[1 + e] = l;
      float dd = l - 0.125f;
      lb += dd * dd;
    }
    off[NEXP] = o;
    out_tail[0] = lb;
  }
  __syncthreads();

  int pos[NEXP];
#pragma unroll
  for (int e = 0; e < NEXP; ++e)
    pos[e] = ebase[e] + wbase[e][wv] + (inc[e] - c[e]);

#pragma unroll
  for (int j = 0; j < 8; ++j) {
    int e = ids[j];
    int p = 0;
#pragma unroll
    for (int k = 0; k < NEXP; ++k)
      if (e == k) { p = pos[k]; pos[k] = p + 1; }
    list[p] = tid * 8 + j;
  }
}

// ===== BK=32 tile: row-pair packed LDS, 2-way-free swizzle (round-8 proven) =====
// byte(r, kq) = (r>>1)*128 + (((kq + (r&1)*4) ^ ((r>>1)&7)) << 4)
// Staged linearly by gl16 from pre-swizzled per-lane global sources.

// ---------- GEMM1: H = gelu(Xg @ W1 + b1); counted-vmcnt dbuf BK=32 ----------
__global__ __launch_bounds__(256) void gemm1_kernel(
    const unsigned short* __restrict__ xb,
    const unsigned short* __restrict__ w1t,   // [E][2048][512]
    const float* __restrict__ b1,
    const int* __restrict__ off,
    const int* __restrict__ list,
    unsigned short* __restrict__ H) {
  int e = blockIdx.x;                        // linear%8 == e -> expert pinned to one XCD
  int offe = off[e];
  int cnt_e = off[e + 1] - offe;
  int n0 = blockIdx.y * 128;
  int m0 = blockIdx.z * 128;
  if (m0 >= cnt_e) return;

  __shared__ char ldsb[36864];   // 2 x (A 8K | B 8K) = 32K; epilogue uses 34816

  int tid = threadIdx.x, wv = tid >> 6, lane = tid & 63;
  int rp = lane >> 3, sl = lane & 7;
  int sx = sl ^ rp;
  int rowadd = rp * 2 + (sx >> 2);
  int kq = sx & 3;

  const unsigned short* w1e = w1t + (size_t)e * HIDN * DIMD;
  const unsigned short* asrc[2];
  const unsigned short* bsrc[2];
#pragma unroll
  for (int i = 0; i < 2; ++i) {
    int r = wv * 32 + i * 16 + rowadd;
    int rr = m0 + r;
    int tok = 0;
    if (rr < cnt_e) tok = list[offe + rr] >> 1;
    asrc[i] = xb + (size_t)tok * DIMD + kq * 8;
    bsrc[i] = w1e + (size_t)(n0 + r) * DIMD + kq * 8;
  }
  int dstA0 = wv * 2048;
  int dstA1 = wv * 2048 + 1024;

  f32x4 zero = {0.f, 0.f, 0.f, 0.f};
  f32x4 acc[4][4];
#pragma unroll
  for (int m = 0; m < 4; ++m)
#pragma unroll
    for (int n = 0; n < 4; ++n) acc[m][n] = zero;

  int wave_m = wv >> 1, wave_n = wv & 1;
  int lane16 = lane & 15, kq4 = lane >> 4;
  int ra[4], rb[4];
#pragma unroll
  for (int m = 0; m < 4; ++m) {
    int r = wave_m * 64 + m * 16 + lane16;
    ra[m] = (r >> 1) * 128 + ((((kq4 + (r & 1) * 4)) ^ ((r >> 1) & 7)) << 4);
    int rn = wave_n * 64 + m * 16 + lane16;
    rb[m] = (rn >> 1) * 128 + ((((kq4 + (rn & 1) * 4)) ^ ((rn >> 1) & 7)) << 4);
  }

  auto stage = [&](char* nb, int k0) {
    gl16(asrc[0] + k0, nb + dstA0);
    gl16(asrc[1] + k0, nb + dstA1);
    gl16(bsrc[0] + k0, nb + 8192 + dstA0);
    gl16(bsrc[1] + k0, nb + 8192 + dstA1);
  };
  auto compute = [&](const char* cb) {
    bf16x8 af[4], bfr[4];
#pragma unroll
    for (int m = 0; m < 4; ++m) af[m] = *reinterpret_cast<const bf16x8*>(cb + ra[m]);
#pragma unroll
    for (int n = 0; n < 4; ++n) bfr[n] = *reinterpret_cast<const bf16x8*>(cb + 8192 + rb[n]);
#pragma unroll
    for (int m = 0; m < 4; ++m)
#pragma unroll
      for (int n = 0; n < 4; ++n)
        acc[m][n] = __builtin_amdgcn_mfma_f32_16x16x32_bf16(af[m], bfr[n], acc[m][n], 0, 0, 0);
  };

  const int T = DIMD / 32;   // 16 steps
  stage(ldsb, 0);
  stage(ldsb + 16384, 32);
  for (int t = 0; t < T - 2; ++t) {
    char* cb = ldsb + (t & 1) * 16384;
    PIPE_WAIT4_BAR();          // tile t ready; tile t+1 stays in flight
    compute(cb);
    PIPE_POST_BAR();           // all waves done reading buf[t&1]
    stage(cb, (t + 2) * 32);   // re-stage same buffer with tile t+2
  }
  PIPE_WAIT4_BAR();
  compute(ldsb + ((T - 2) & 1) * 16384);
  PIPE_POST_BAR();
  PIPE_WAIT0_BAR();
  compute(ldsb + ((T - 1) & 1) * 16384);
  PIPE_POST_BAR();             // vmcnt==0 per wave; LDS reuse below is safe

  // epilogue: gelu -> bf16 C-tile in LDS (stride 136 shorts), coalesced uint4 store
  unsigned short* Ct = (unsigned short*)ldsb;
  const float* b1e = b1 + e * HIDN;
#pragma unroll
  for (int n = 0; n < 4; ++n) {
    int cl = wave_n * 64 + n * 16 + lane16;
    float bias = b1e[n0 + cl];
#pragma unroll
    for (int m = 0; m < 4; ++m) {
#pragma unroll
      for (int q = 0; q < 4; ++q) {
        int rl = wave_m * 64 + m * 16 + kq4 * 4 + q;
        float v = acc[m][n][q] + bias;
        float g = 0.5f * v * (1.f + erff(v * 0.70710678118654752f));
        Ct[rl * 136 + cl] = f2bf(g);
      }
    }
  }
  __syncthreads();
  for (int u = tid; u < 2048; u += 256) {
    int rl = u >> 4, c8 = (u & 15) * 8;
    int r = m0 + rl;
    if (r < cnt_e) {
      uint4 v = *reinterpret_cast<const uint4*>(Ct + rl * 136 + c8);
      *reinterpret_cast<uint4*>(H + (size_t)(offe + r) * HIDN + n0 + c8) = v;
    }
  }
}

// ---------- GEMM2: Yw[a] = tw[a]*(H @ W2 + b2); counted-vmcnt dbuf BK=32 ----------
__global__ __launch_bounds__(256) void gemm2_kernel(
    const unsigned short* __restrict__ H,
    const unsigned short* __restrict__ w2t,   // [E][512][2048]
    const float* __restrict__ b2,
    const int* __restrict__ off,
    const int* __restrict__ list,
    const float* __restrict__ tw,
    float* __restrict__ Yw) {
  int e = blockIdx.x;
  int offe = off[e];
  int cnt_e = off[e + 1] - offe;
  int n0 = blockIdx.y * 128;
  int m0 = blockIdx.z * 128;
  if (m0 >= cnt_e) return;

  __shared__ char ldsb[32768];

  int tid = threadIdx.x, wv = tid >> 6, lane = tid & 63;
  int rp = lane >> 3, sl = lane & 7;
  int sx = sl ^ rp;
  int rowadd = rp * 2 + (sx >> 2);
  int kq = sx & 3;

  const unsigned short* w2e = w2t + (size_t)e * DIMD * HIDN;
  const unsigned short* asrc[2];
  const unsigned short* bsrc[2];
#pragma unroll
  for (int i = 0; i < 2; ++i) {
    int r = wv * 32 + i * 16 + rowadd;
    int rowa = offe + m0 + r;
    if (rowa > NASG - 1) rowa = NASG - 1;    // pad rows: clamp (values discarded)
    asrc[i] = H + (size_t)rowa * HIDN + kq * 8;
    bsrc[i] = w2e + (size_t)(n0 + r) * HIDN + kq * 8;
  }
  int dstA0 = wv * 2048;
  int dstA1 = wv * 2048 + 1024;

  f32x4 zero = {0.f, 0.f, 0.f, 0.f};
  f32x4 acc[4][4];
#pragma unroll
  for (int m = 0; m < 4; ++m)
#pragma unroll
    for (int n = 0; n < 4; ++n) acc[m][n] = zero;

  int wave_m = wv >> 1, wave_n = wv & 1;
  int lane16 = lane & 15, kq4 = lane >> 4;
  int ra[4], rb[4];
#pragma unroll
  for (int m = 0; m < 4; ++m) {
    int r = wave_m * 64 + m * 16 + lane16;
    ra[m] = (r >> 1) * 128 + ((((kq4 + (r & 1) * 4)) ^ ((r >> 1) & 7)) << 4);
    int rn = wave_n * 64 + m * 16 + lane16;
    rb[m] = (rn >> 1) * 128 + ((((kq4 + (rn & 1) * 4)) ^ ((rn >> 1) & 7)) << 4);
  }

  auto stage = [&](char* nb, int k0) {
    gl16(asrc[0] + k0, nb + dstA0);
    gl16(asrc[1] + k0, nb + dstA1);
    gl16(bsrc[0] + k0, nb + 8192 + dstA0);
    gl16(bsrc[1] + k0, nb + 8192 + dstA1);
  };
  auto compute = [&](const char* cb) {
    bf16x8 af[4], bfr[4];
#pragma unroll
    for (int m = 0; m < 4; ++m) af[m] = *reinterpret_cast<const bf16x8*>(cb + ra[m]);
#pragma unroll
    for (int n = 0; n < 4; ++n) bfr[n] = *reinterpret_cast<const bf16x8*>(cb + 8192 + rb[n]);
#pragma unroll
    for (int m = 0; m < 4; ++m)
#pragma unroll
      for (int n = 0; n < 4; ++n)
        acc[m][n] = __builtin_amdgcn_mfma_f32_16x16x32_bf16(af[m], bfr[n], acc[m][n], 0, 0, 0);
  };

  const int T = HIDN / 32;   // 64 steps
  stage(ldsb, 0);
  stage(ldsb + 16384, 32);
  for (int t = 0; t < T - 2; ++t) {
    char* cb = ldsb + (t & 1) * 16384;
    PIPE_WAIT4_BAR();
    compute(cb);
    PIPE_POST_BAR();
    stage(cb, (t + 2) * 32);
  }
  PIPE_WAIT4_BAR();
  compute(ldsb + ((T - 2) & 1) * 16384);
  PIPE_POST_BAR();
  PIPE_WAIT0_BAR();
  compute(ldsb + ((T - 1) & 1) * 16384);
  PIPE_POST_BAR();

  const float* b2e = b2 + e * DIMD;
  float bias[4];
#pragma unroll
  for (int n = 0; n < 4; ++n) bias[n] = b2e[n0 + wave_n * 64 + n * 16 + lane16];
#pragma unroll
  for (int m = 0; m < 4; ++m) {
#pragma unroll
    for (int q = 0; q < 4; ++q) {
      int r = m0 + wave_m * 64 + m * 16 + kq4 * 4 + q;
      if (r < cnt_e) {
        int a = list[offe + r];
        float w = tw[a];
        float* yrow = Yw + (size_t)a * DIMD;
#pragma unroll
        for (int n = 0; n < 4; ++n) {
          int col = n0 + wave_n * 64 + n * 16 + lane16;
          yrow[col] = w * (acc[m][n][q] + bias[n]);
        }
      }
    }
  }
}

// ---------- combine: out[n] = Yw[2n] + Yw[2n+1] ----------
__global__ __launch_bounds__(256) void combine_kernel(const float* __restrict__ Yw,
                                                      float* __restrict__ out) {
  int i = (blockIdx.x * 256 + threadIdx.x) * 4;
  int n = i >> 9;
  int d = i & 511;
  float4 a = *reinterpret_cast<const float4*>(Yw + (size_t)(2 * n) * DIMD + d);
  float4 b = *reinterpret_cast<const float4*>(Yw + (size_t)(2 * n + 1) * DIMD + d);
  float4 o;
  o.x = a.x + b.x; o.y = a.y + b.y; o.z = a.z + b.z; o.w = a.w + b.w;
  *reinterpret_cast<float4*>(out + i) = o;
}

extern "C" void kernel_launch(void* const* d_in, const int* in_sizes, int n_in,
                              void* d_out, int out_size, void* d_ws, size_t ws_size,
                              hipStream_t stream) {
  const float* x  = (const float*)d_in[0];
  const float* Wr = (const float*)d_in[1];
  const float* br = (const float*)d_in[2];
  const float* W1 = (const float*)d_in[3];
  const float* b1 = (const float*)d_in[4];
  const float* W2 = (const float*)d_in[5];
  const float* b2 = (const float*)d_in[6];
  float* out = (float*)d_out;

  char* ws = (char*)d_ws;
  unsigned short* xb  = (unsigned short*)ws;  ws += (size_t)NTOK * DIMD * 2;
  unsigned short* w1t = (unsigned short*)ws;  ws += (size_t)NEXP * HIDN * DIMD * 2;
  unsigned short* w2t = (unsigned short*)ws;  ws += (size_t)NEXP * DIMD * HIDN * 2;
  unsigned short* H   = (unsigned short*)ws;  ws += (size_t)NASG * HIDN * 2;
  float* Yw = (float*)ws;                     ws += (size_t)NASG * DIMD * 4;
  float* tw = (float*)ws;                     ws += (size_t)NASG * 4;
  int* tidx = (int*)ws;                       ws += (size_t)NASG * 4;
  int* list = (int*)ws;                       ws += (size_t)NASG * 4;
  int* offp = (int*)ws;                       // off[9]

  transpose_both_kernel<<<dim3(32, 8, 16), 256, 0, stream>>>(W1, W2, w1t, w2t);
  router_kernel<<<NTOK / 4, 256, 0, stream>>>(x, Wr, br, tidx, tw, xb);
  route_pack_kernel<<<1, 1024, 0, stream>>>(tidx, offp, list, out + (size_t)NTOK * DIMD);
  // expert = blockIdx.x -> grid-linear %8 == expert -> XCD-pinned weight panels
  gemm1_kernel<<<dim3(NEXP, HIDN / 128, NASG / 128), 256, 0, stream>>>(xb, w1t, b1, offp, list, H);
  gemm2_kernel<<<dim3(NEXP, DIMD / 128, NASG / 128), 256, 0, stream>>>(H, w2t, b2, offp, list, tw, Yw);
  combine_kernel<<<2048, 256, 0, stream>>>(Yw, out);
}

// Round 15
// 117.077 us; speedup vs baseline: 2.0321x; 1.0123x over previous
//
#include <hip/hip_runtime.h>
#include <hip/hip_bf16.h>

#define DIMD 512
#define NEXP 8
#define HIDN 2048
#define NTOK 4096
#define NASG 8192

typedef short bf16x8 __attribute__((ext_vector_type(8)));
typedef float f32x4 __attribute__((ext_vector_type(4)));

__device__ inline unsigned short f2bf(float f) {
  __hip_bfloat16 h = __float2bfloat16(f);
  return __builtin_bit_cast(unsigned short, h);
}

__device__ inline void gl16(const void* g, void* l) {
  __builtin_amdgcn_global_load_lds(
      (const __attribute__((address_space(1))) unsigned int*)g,
      (__attribute__((address_space(3))) unsigned int*)l, 16, 0, 0);
}

// Counted-vmcnt barrier discipline: wait only the OLDER stage's loads.
#define PIPE_WAIT4_BAR() do { \
  asm volatile("s_waitcnt vmcnt(4)" ::: "memory"); \
  __builtin_amdgcn_s_barrier(); \
  __builtin_amdgcn_sched_barrier(0); } while (0)
#define PIPE_WAIT0_BAR() do { \
  asm volatile("s_waitcnt vmcnt(0)" ::: "memory"); \
  __builtin_amdgcn_s_barrier(); \
  __builtin_amdgcn_sched_barrier(0); } while (0)
#define PIPE_POST_BAR() do { \
  asm volatile("" ::: "memory"); \
  __builtin_amdgcn_sched_barrier(0); \
  __builtin_amdgcn_s_barrier(); } while (0)

// ---------- both W transposes in one launch: [E][R][C] fp32 -> [E][C][R] bf16 ----------
__global__ __launch_bounds__(256) void transpose_both_kernel(
    const float* __restrict__ W1, const float* __restrict__ W2,
    unsigned short* __restrict__ w1t, unsigned short* __restrict__ w2t) {
  __shared__ float tile[64][65];
  int z = blockIdx.z;
  int e = z & 7;
  const float* src; unsigned short* dst; int R, C, r0, c0;
  if (z < 8) { src = W1; dst = w1t; R = DIMD; C = HIDN; c0 = blockIdx.x * 64; r0 = blockIdx.y * 64; }
  else       { src = W2; dst = w2t; R = HIDN; C = DIMD; r0 = blockIdx.x * 64; c0 = blockIdx.y * 64; }
  const float* s = src + (size_t)e * R * C;
  unsigned short* d = dst + (size_t)e * R * C;
  // float4 coalesced reads
  for (int i = threadIdx.x; i < 1024; i += 256) {
    int r = i >> 4, c4 = (i & 15) * 4;
    float4 v = *reinterpret_cast<const float4*>(s + (size_t)(r0 + r) * C + (c0 + c4));
    tile[r][c4] = v.x; tile[r][c4 + 1] = v.y; tile[r][c4 + 2] = v.z; tile[r][c4 + 3] = v.w;
  }
  __syncthreads();
  // uint2 packed writes (4 consecutive r per thread)
  for (int i = threadIdx.x; i < 1024; i += 256) {
    int c = i >> 4;
    int r = (i & 15) * 4;
    unsigned u0 = (unsigned)f2bf(tile[r][c]) | ((unsigned)f2bf(tile[r + 1][c]) << 16);
    unsigned u1 = (unsigned)f2bf(tile[r + 2][c]) | ((unsigned)f2bf(tile[r + 3][c]) << 16);
    *reinterpret_cast<uint2*>(d + (size_t)(c0 + c) * R + (r0 + r)) = make_uint2(u0, u1);
  }
}

// ---------- router: lane l owns d=8l..8l+7; all-vector loads. NO atomics. ----------
__global__ __launch_bounds__(256) void router_kernel(const float* __restrict__ x,
                                                     const float* __restrict__ Wr,
                                                     const float* __restrict__ br,
                                                     int* __restrict__ tidx,
                                                     float* __restrict__ tw,
                                                     unsigned short* __restrict__ xb) {
  int lane = threadIdx.x & 63;
  int n = blockIdx.x * 4 + (threadIdx.x >> 6);
  const float* xr = x + (size_t)n * DIMD;
  unsigned short* xbr = xb + (size_t)n * DIMD;
  int d0 = lane * 8;                         // 64 lanes x 8 = 512 = DIMD
  float4 xa = *reinterpret_cast<const float4*>(xr + d0);
  float4 xc = *reinterpret_cast<const float4*>(xr + d0 + 4);
  uint4 pk;
  pk.x = (unsigned)f2bf(xa.x) | ((unsigned)f2bf(xa.y) << 16);
  pk.y = (unsigned)f2bf(xa.z) | ((unsigned)f2bf(xa.w) << 16);
  pk.z = (unsigned)f2bf(xc.x) | ((unsigned)f2bf(xc.y) << 16);
  pk.w = (unsigned)f2bf(xc.z) | ((unsigned)f2bf(xc.w) << 16);
  *reinterpret_cast<uint4*>(xbr + d0) = pk;   // lane*16 bytes, aligned

  float acc[NEXP];
#pragma unroll
  for (int e = 0; e < NEXP; ++e) acc[e] = 0.f;
  const float* wr = Wr + (size_t)d0 * NEXP;   // 64 consecutive floats per lane
#pragma unroll
  for (int j = 0; j < 8; ++j) {
    float xj = (j < 4) ? (&xa.x)[j] : (&xc.x)[j - 4];
    float4 w0 = *reinterpret_cast<const float4*>(wr + j * NEXP);
    float4 w1 = *reinterpret_cast<const float4*>(wr + j * NEXP + 4);
    acc[0] += xj * w0.x; acc[1] += xj * w0.y; acc[2] += xj * w0.z; acc[3] += xj * w0.w;
    acc[4] += xj * w1.x; acc[5] += xj * w1.y; acc[6] += xj * w1.z; acc[7] += xj * w1.w;
  }
#pragma unroll
  for (int e = 0; e < NEXP; ++e) {
    float v = acc[e];
#pragma unroll
    for (int off = 32; off > 0; off >>= 1) v += __shfl_xor(v, off, 64);
    acc[e] = v + br[e];
  }
  if (lane == 0) {
    float m = acc[0];
    for (int e = 1; e < NEXP; ++e) m = fmaxf(m, acc[e]);
    float p[NEXP], s = 0.f;
    for (int e = 0; e < NEXP; ++e) { p[e] = expf(acc[e] - m); s += p[e]; }
    float inv = 1.f / s;
    for (int e = 0; e < NEXP; ++e) p[e] *= inv;
    int i0 = 0; float p0 = p[0];
    for (int e = 1; e < NEXP; ++e) if (p[e] > p0) { p0 = p[e]; i0 = e; }
    int i1 = (i0 == 0) ? 1 : 0; float p1 = p[i1];
    for (int e = 0; e < NEXP; ++e) if (e != i0 && p[e] > p1) { p1 = p[e]; i1 = e; }
    // reference renormalizes by softmax over the top-2 *probabilities*
    float t = expf(p1 - p0);
    float w0 = 1.f / (1.f + t);
    tidx[2 * n] = i0; tidx[2 * n + 1] = i1;
    tw[2 * n] = w0; tw[2 * n + 1] = t * w0;
  }
}

// ---------- route_pack: counts + offsets + stable scatter + lb tail, single block ----------
__global__ __launch_bounds__(1024) void route_pack_kernel(const int* __restrict__ tidx,
                                                          int* __restrict__ off,
                                                          int* __restrict__ list,
                                                          float* __restrict__ out_tail) {
  int tid = threadIdx.x;
  int wv = tid >> 6, lane = tid & 63;

  int ids[8];
#pragma unroll
  for (int j = 0; j < 8; ++j) ids[j] = tidx[tid * 8 + j];

  int c[NEXP];
#pragma unroll
  for (int e = 0; e < NEXP; ++e) c[e] = 0;
#pragma unroll
  for (int j = 0; j < 8; ++j)
#pragma unroll
    for (int e = 0; e < NEXP; ++e) c[e] += (ids[j] == e) ? 1 : 0;

  int inc[NEXP];
#pragma unroll
  for (int e = 0; e < NEXP; ++e) {
    int v = c[e];
#pragma unroll
    for (int d = 1; d < 64; d <<= 1) {
      int t = __shfl_up(v, d, 64);
      if (lane >= d) v += t;
    }
    inc[e] = v;
  }

  __shared__ int wtot[NEXP][16];
  __shared__ int wbase[NEXP][16];
  __shared__ int ebase[NEXP];
  if (lane == 63) {
#pragma unroll
    for (int e = 0; e < NEXP; ++e) wtot[e][wv] = inc[e];
  }
  __syncthreads();
  // 8-lane parallel (wave 0, lanes 0..7): per-expert wave-scan + cross-expert prefix
  if (tid < NEXP) {
    int e = tid;
    int s = 0;
#pragma unroll
    for (int w = 0; w < 16; ++w) { wbase[e][w] = s; s += wtot[e][w]; }
    int pfx = s;                              // inclusive prefix over experts
#pragma unroll
    for (int d = 1; d < 8; d <<= 1) {
      int t = __shfl_up(pfx, d, 64);          // sources stay in lanes 0..7 (active)
      if (tid >= d) pfx += t;
    }
    int base = pfx - s;                       // exclusive
    ebase[e] = base;
    off[e] = base;
    if (e == NEXP - 1) off[NEXP] = pfx;
    float l = (float)s / (float)NASG;
    out_tail[1 + e] = l;
    float dd = l - 0.125f;
    float lb = dd * dd;
#pragma unroll
    for (int d = 1; d < 8; d <<= 1) lb += __shfl_xor(lb, d, 64);  // xor keeps lanes 0..7
    if (e == 0) out_tail[0] = lb;
  }
  __syncthreads();

  int pos[NEXP];
#pragma unroll
  for (int e = 0; e < NEXP; ++e)
    pos[e] = ebase[e] + wbase[e][wv] + (inc[e] - c[e]);

#pragma unroll
  for (int j = 0; j < 8; ++j) {
    int e = ids[j];
    int p = 0;
#pragma unroll
    for (int k = 0; k < NEXP; ++k)
      if (e == k) { p = pos[k]; pos[k] = p + 1; }
    list[p] = tid * 8 + j;
  }
}

// ===== BK=32 tile: row-pair packed LDS, 2-way-free swizzle (round-8 proven) =====
// byte(r, kq) = (r>>1)*128 + (((kq + (r&1)*4) ^ ((r>>1)&7)) << 4)
// Staged linearly by gl16 from pre-swizzled per-lane global sources.

// ---------- GEMM1: H = gelu(Xg @ W1 + b1); counted-vmcnt dbuf BK=32 ----------
__global__ __launch_bounds__(256) void gemm1_kernel(
    const unsigned short* __restrict__ xb,
    const unsigned short* __restrict__ w1t,   // [E][2048][512]
    const float* __restrict__ b1,
    const int* __restrict__ off,
    const int* __restrict__ list,
    unsigned short* __restrict__ H) {
  int e = blockIdx.x;                        // linear%8 == e -> expert pinned to one XCD
  int offe = off[e];
  int cnt_e = off[e + 1] - offe;
  int n0 = blockIdx.y * 128;
  int m0 = blockIdx.z * 128;
  if (m0 >= cnt_e) return;

  __shared__ char ldsb[36864];   // 2 x (A 8K | B 8K) = 32K; epilogue uses 34816

  int tid = threadIdx.x, wv = tid >> 6, lane = tid & 63;
  int rp = lane >> 3, sl = lane & 7;
  int sx = sl ^ rp;
  int rowadd = rp * 2 + (sx >> 2);
  int kq = sx & 3;

  const unsigned short* w1e = w1t + (size_t)e * HIDN * DIMD;
  const unsigned short* asrc[2];
  const unsigned short* bsrc[2];
#pragma unroll
  for (int i = 0; i < 2; ++i) {
    int r = wv * 32 + i * 16 + rowadd;
    int rr = m0 + r;
    int tok = 0;
    if (rr < cnt_e) tok = list[offe + rr] >> 1;
    asrc[i] = xb + (size_t)tok * DIMD + kq * 8;
    bsrc[i] = w1e + (size_t)(n0 + r) * DIMD + kq * 8;
  }
  int dstA0 = wv * 2048;
  int dstA1 = wv * 2048 + 1024;

  f32x4 zero = {0.f, 0.f, 0.f, 0.f};
  f32x4 acc[4][4];
#pragma unroll
  for (int m = 0; m < 4; ++m)
#pragma unroll
    for (int n = 0; n < 4; ++n) acc[m][n] = zero;

  int wave_m = wv >> 1, wave_n = wv & 1;
  int lane16 = lane & 15, kq4 = lane >> 4;
  int ra[4], rb[4];
#pragma unroll
  for (int m = 0; m < 4; ++m) {
    int r = wave_m * 64 + m * 16 + lane16;
    ra[m] = (r >> 1) * 128 + ((((kq4 + (r & 1) * 4)) ^ ((r >> 1) & 7)) << 4);
    int rn = wave_n * 64 + m * 16 + lane16;
    rb[m] = (rn >> 1) * 128 + ((((kq4 + (rn & 1) * 4)) ^ ((rn >> 1) & 7)) << 4);
  }

  auto stage = [&](char* nb, int k0) {
    gl16(asrc[0] + k0, nb + dstA0);
    gl16(asrc[1] + k0, nb + dstA1);
    gl16(bsrc[0] + k0, nb + 8192 + dstA0);
    gl16(bsrc[1] + k0, nb + 8192 + dstA1);
  };
  auto compute = [&](const char* cb) {
    bf16x8 af[4], bfr[4];
#pragma unroll
    for (int m = 0; m < 4; ++m) af[m] = *reinterpret_cast<const bf16x8*>(cb + ra[m]);
#pragma unroll
    for (int n = 0; n < 4; ++n) bfr[n] = *reinterpret_cast<const bf16x8*>(cb + 8192 + rb[n]);
#pragma unroll
    for (int m = 0; m < 4; ++m)
#pragma unroll
      for (int n = 0; n < 4; ++n)
        acc[m][n] = __builtin_amdgcn_mfma_f32_16x16x32_bf16(af[m], bfr[n], acc[m][n], 0, 0, 0);
  };

  const int T = DIMD / 32;   // 16 steps
  stage(ldsb, 0);
  stage(ldsb + 16384, 32);
  for (int t = 0; t < T - 2; ++t) {
    char* cb = ldsb + (t & 1) * 16384;
    PIPE_WAIT4_BAR();          // tile t ready; tile t+1 stays in flight
    compute(cb);
    PIPE_POST_BAR();           // all waves done reading buf[t&1]
    stage(cb, (t + 2) * 32);   // re-stage same buffer with tile t+2
  }
  PIPE_WAIT4_BAR();
  compute(ldsb + ((T - 2) & 1) * 16384);
  PIPE_POST_BAR();
  PIPE_WAIT0_BAR();
  compute(ldsb + ((T - 1) & 1) * 16384);
  PIPE_POST_BAR();             // vmcnt==0 per wave; LDS reuse below is safe

  // epilogue: gelu -> bf16 C-tile in LDS (stride 136 shorts), coalesced uint4 store
  unsigned short* Ct = (unsigned short*)ldsb;
  const float* b1e = b1 + e * HIDN;
#pragma unroll
  for (int n = 0; n < 4; ++n) {
    int cl = wave_n * 64 + n * 16 + lane16;
    float bias = b1e[n0 + cl];
#pragma unroll
    for (int m = 0; m < 4; ++m) {
#pragma unroll
      for (int q = 0; q < 4; ++q) {
        int rl = wave_m * 64 + m * 16 + kq4 * 4 + q;
        float v = acc[m][n][q] + bias;
        float g = 0.5f * v * (1.f + erff(v * 0.70710678118654752f));
        Ct[rl * 136 + cl] = f2bf(g);
      }
    }
  }
  __syncthreads();
  for (int u = tid; u < 2048; u += 256) {
    int rl = u >> 4, c8 = (u & 15) * 8;
    int r = m0 + rl;
    if (r < cnt_e) {
      uint4 v = *reinterpret_cast<const uint4*>(Ct + rl * 136 + c8);
      *reinterpret_cast<uint4*>(H + (size_t)(offe + r) * HIDN + n0 + c8) = v;
    }
  }
}

// ---------- GEMM2: Yw[a] = tw[a]*(H @ W2 + b2); counted-vmcnt dbuf BK=32 ----------
__global__ __launch_bounds__(256) void gemm2_kernel(
    const unsigned short* __restrict__ H,
    const unsigned short* __restrict__ w2t,   // [E][512][2048]
    const float* __restrict__ b2,
    const int* __restrict__ off,
    const int* __restrict__ list,
    const float* __restrict__ tw,
    float* __restrict__ Yw) {
  int e = blockIdx.x;
  int offe = off[e];
  int cnt_e = off[e + 1] - offe;
  int n0 = blockIdx.y * 128;
  int m0 = blockIdx.z * 128;
  if (m0 >= cnt_e) return;

  __shared__ char ldsb[32768];

  int tid = threadIdx.x, wv = tid >> 6, lane = tid & 63;
  int rp = lane >> 3, sl = lane & 7;
  int sx = sl ^ rp;
  int rowadd = rp * 2 + (sx >> 2);
  int kq = sx & 3;

  const unsigned short* w2e = w2t + (size_t)e * DIMD * HIDN;
  const unsigned short* asrc[2];
  const unsigned short* bsrc[2];
#pragma unroll
  for (int i = 0; i < 2; ++i) {
    int r = wv * 32 + i * 16 + rowadd;
    int rowa = offe + m0 + r;
    if (rowa > NASG - 1) rowa = NASG - 1;    // pad rows: clamp (values discarded)
    asrc[i] = H + (size_t)rowa * HIDN + kq * 8;
    bsrc[i] = w2e + (size_t)(n0 + r) * HIDN + kq * 8;
  }
  int dstA0 = wv * 2048;
  int dstA1 = wv * 2048 + 1024;

  f32x4 zero = {0.f, 0.f, 0.f, 0.f};
  f32x4 acc[4][4];
#pragma unroll
  for (int m = 0; m < 4; ++m)
#pragma unroll
    for (int n = 0; n < 4; ++n) acc[m][n] = zero;

  int wave_m = wv >> 1, wave_n = wv & 1;
  int lane16 = lane & 15, kq4 = lane >> 4;
  int ra[4], rb[4];
#pragma unroll
  for (int m = 0; m < 4; ++m) {
    int r = wave_m * 64 + m * 16 + lane16;
    ra[m] = (r >> 1) * 128 + ((((kq4 + (r & 1) * 4)) ^ ((r >> 1) & 7)) << 4);
    int rn = wave_n * 64 + m * 16 + lane16;
    rb[m] = (rn >> 1) * 128 + ((((kq4 + (rn & 1) * 4)) ^ ((rn >> 1) & 7)) << 4);
  }

  auto stage = [&](char* nb, int k0) {
    gl16(asrc[0] + k0, nb + dstA0);
    gl16(asrc[1] + k0, nb + dstA1);
    gl16(bsrc[0] + k0, nb + 8192 + dstA0);
    gl16(bsrc[1] + k0, nb + 8192 + dstA1);
  };
  auto compute = [&](const char* cb) {
    bf16x8 af[4], bfr[4];
#pragma unroll
    for (int m = 0; m < 4; ++m) af[m] = *reinterpret_cast<const bf16x8*>(cb + ra[m]);
#pragma unroll
    for (int n = 0; n < 4; ++n) bfr[n] = *reinterpret_cast<const bf16x8*>(cb + 8192 + rb[n]);
#pragma unroll
    for (int m = 0; m < 4; ++m)
#pragma unroll
      for (int n = 0; n < 4; ++n)
        acc[m][n] = __builtin_amdgcn_mfma_f32_16x16x32_bf16(af[m], bfr[n], acc[m][n], 0, 0, 0);
  };

  const int T = HIDN / 32;   // 64 steps
  stage(ldsb, 0);
  stage(ldsb + 16384, 32);
  for (int t = 0; t < T - 2; ++t) {
    char* cb = ldsb + (t & 1) * 16384;
    PIPE_WAIT4_BAR();
    compute(cb);
    PIPE_POST_BAR();
    stage(cb, (t + 2) * 32);
  }
  PIPE_WAIT4_BAR();
  compute(ldsb + ((T - 2) & 1) * 16384);
  PIPE_POST_BAR();
  PIPE_WAIT0_BAR();
  compute(ldsb + ((T - 1) & 1) * 16384);
  PIPE_POST_BAR();

  const float* b2e = b2 + e * DIMD;
  float bias[4];
#pragma unroll
  for (int n = 0; n < 4; ++n) bias[n] = b2e[n0 + wave_n * 64 + n * 16 + lane16];
#pragma unroll
  for (int m = 0; m < 4; ++m) {
#pragma unroll
    for (int q = 0; q < 4; ++q) {
      int r = m0 + wave_m * 64 + m * 16 + kq4 * 4 + q;
      if (r < cnt_e) {
        int a = list[offe + r];
        float w = tw[a];
        float* yrow = Yw + (size_t)a * DIMD;
#pragma unroll
        for (int n = 0; n < 4; ++n) {
          int col = n0 + wave_n * 64 + n * 16 + lane16;
          yrow[col] = w * (acc[m][n][q] + bias[n]);
        }
      }
    }
  }
}

// ---------- combine: out[n] = Yw[2n] + Yw[2n+1] ----------
__global__ __launch_bounds__(256) void combine_kernel(const float* __restrict__ Yw,
                                                      float* __restrict__ out) {
  int i = (blockIdx.x * 256 + threadIdx.x) * 4;
  int n = i >> 9;
  int d = i & 511;
  float4 a = *reinterpret_cast<const float4*>(Yw + (size_t)(2 * n) * DIMD + d);
  float4 b = *reinterpret_cast<const float4*>(Yw + (size_t)(2 * n + 1) * DIMD + d);
  float4 o;
  o.x = a.x + b.x; o.y = a.y + b.y; o.z = a.z + b.z; o.w = a.w + b.w;
  *reinterpret_cast<float4*>(out + i) = o;
}

extern "C" void kernel_launch(void* const* d_in, const int* in_sizes, int n_in,
                              void* d_out, int out_size, void* d_ws, size_t ws_size,
                              hipStream_t stream) {
  const float* x  = (const float*)d_in[0];
  const float* Wr = (const float*)d_in[1];
  const float* br = (const float*)d_in[2];
  const float* W1 = (const float*)d_in[3];
  const float* b1 = (const float*)d_in[4];
  const float* W2 = (const float*)d_in[5];
  const float* b2 = (const float*)d_in[6];
  float* out = (float*)d_out;

  char* ws = (char*)d_ws;
  unsigned short* xb  = (unsigned short*)ws;  ws += (size_t)NTOK * DIMD * 2;
  unsigned short* w1t = (unsigned short*)ws;  ws += (size_t)NEXP * HIDN * DIMD * 2;
  unsigned short* w2t = (unsigned short*)ws;  ws += (size_t)NEXP * DIMD * HIDN * 2;
  unsigned short* H   = (unsigned short*)ws;  ws += (size_t)NASG * HIDN * 2;
  float* Yw = (float*)ws;                     ws += (size_t)NASG * DIMD * 4;
  float* tw = (float*)ws;                     ws += (size_t)NASG * 4;
  int* tidx = (int*)ws;                       ws += (size_t)NASG * 4;
  int* list = (int*)ws;                       ws += (size_t)NASG * 4;
  int* offp = (int*)ws;                       // off[9]

  transpose_both_kernel<<<dim3(32, 8, 16), 256, 0, stream>>>(W1, W2, w1t, w2t);
  router_kernel<<<NTOK / 4, 256, 0, stream>>>(x, Wr, br, tidx, tw, xb);
  route_pack_kernel<<<1, 1024, 0, stream>>>(tidx, offp, list, out + (size_t)NTOK * DIMD);
  // expert = blockIdx.x -> grid-linear %8 == expert -> XCD-pinned weight panels
  gemm1_kernel<<<dim3(NEXP, HIDN / 128, NASG / 128), 256, 0, stream>>>(xb, w1t, b1, offp, list, H);
  gemm2_kernel<<<dim3(NEXP, DIMD / 128, NASG / 128), 256, 0, stream>>>(H, w2t, b2, offp, list, tw, Yw);
  combine_kernel<<<2048, 256, 0, stream>>>(Yw, out);
}